// Round 6
// baseline (426.232 us; speedup 1.0000x reference)
//
#include <hip/hip_runtime.h>

// B=64, S=512, D=256, VOCAB=50000, NC=10, N_STEPS=10 (h=0.1), BN eval.
// z_final = z0 @ P10 + c10, P10 = M^10, M = Taylor4(exp(hA)), A = W^T.
// Transpose trick: M = N^T, N = I + B, B = 0.1W + 0.005W^2 + (1e-3/6)W^3 + (1e-4/24)W^4,
// so P10 = (N^10)^T; the transpose is absorbed into the slab fragment scatter.
//
// LESSONS (rounds 1-5):
//  - Dispatch boundaries cost ~17-30us each; every removed dispatch paid out.
//    cg::grid.sync is ~110us/sync. k_main is latency-bound (MfmaUtil 26%,
//    depth-1 B prefetch < L2 latency at 2 waves/SIMD).
//  - THIS ROUND: single megakernel, 512 blocks (guaranteed co-resident:
//    36KB LDS -> 4 blocks/CU capacity, need 2). Hand-rolled global barrier
//    (epoch flag + self-resetting counter, agent-scope atomics, s_sleep).
//    R2's cooperative kernel passed correctness -> agent fences do invalidate
//    per-XCD L2 on this chip. Barrier is rocprof-replay-safe.
//  - Main phase: depth-4 B-frag register pipeline (prefetch one full 4-entry
//    group ahead) to cover L2 latency. Finisher classifier with batched loads.

typedef short bf16x8 __attribute__((ext_vector_type(8)));
typedef float f32x4 __attribute__((ext_vector_type(4)));

__device__ __forceinline__ unsigned short f2bf(float f) {
  unsigned u = __float_as_uint(f);
  u += 0x7FFFu + ((u >> 16) & 1u);   // RNE; inputs are normal floats
  return (unsigned short)(u >> 16);
}

// acc_j = sum_k xrow[k] * Y[k][tid]; xrow in LDS, Y global, coalesced.
__device__ __forceinline__ float dotcol(const float* __restrict__ xrow,
                                        const float* __restrict__ Y, int tid) {
  float a0 = 0.f, a1 = 0.f, a2 = 0.f, a3 = 0.f;
#pragma unroll 4
  for (int k = 0; k < 256; k += 16) {
    float bv[16];
#pragma unroll
    for (int u = 0; u < 16; ++u) bv[u] = Y[(k + u) * 256 + tid];
#pragma unroll
    for (int u = 0; u < 16; u += 4) {
      a0 = fmaf(xrow[k + u + 0], bv[u + 0], a0);
      a1 = fmaf(xrow[k + u + 1], bv[u + 1], a1);
      a2 = fmaf(xrow[k + u + 2], bv[u + 2], a2);
      a3 = fmaf(xrow[k + u + 3], bv[u + 3], a3);
    }
  }
  return (a0 + a1) + (a2 + a3);
}

// init + sum_k cvec[k] * row[k]; cvec in LDS, row = one global row (per-thread).
__device__ __forceinline__ float rowscan(const float* __restrict__ cvec,
                                         const float* __restrict__ row, float init) {
  float a0 = init, a1 = 0.f, a2 = 0.f, a3 = 0.f;
#pragma unroll 4
  for (int k = 0; k < 256; k += 16) {
    float bv[16];
#pragma unroll
    for (int u = 0; u < 16; ++u) bv[u] = row[k + u];
#pragma unroll
    for (int u = 0; u < 16; u += 4) {
      a0 = fmaf(cvec[k + u + 0], bv[u + 0], a0);
      a1 = fmaf(cvec[k + u + 1], bv[u + 1], a1);
      a2 = fmaf(cvec[k + u + 2], bv[u + 2], a2);
      a3 = fmaf(cvec[k + u + 3], bv[u + 3], a3);
    }
  }
  return (a0 + a1) + (a2 + a3);
}

// Global barrier for 512 co-resident blocks. Epoch flag + self-resetting
// counter: replay-safe (flag compare is relative; cnt returns to 0).
__device__ __forceinline__ void gbar(unsigned* __restrict__ cnt,
                                     unsigned* __restrict__ flag) {
  __syncthreads();
  if (threadIdx.x == 0) {
    __threadfence();   // release our stores (device scope)
    unsigned my = __hip_atomic_load(flag, __ATOMIC_RELAXED, __HIP_MEMORY_SCOPE_AGENT);
    if (atomicAdd(cnt, 1u) == 511u) {
      __hip_atomic_store(cnt, 0u, __ATOMIC_RELAXED, __HIP_MEMORY_SCOPE_AGENT);
      __hip_atomic_store(flag, my + 1u, __ATOMIC_RELEASE, __HIP_MEMORY_SCOPE_AGENT);
    } else {
      while (__hip_atomic_load(flag, __ATOMIC_RELAXED, __HIP_MEMORY_SCOPE_AGENT) == my)
        __builtin_amdgcn_s_sleep(2);
    }
    __threadfence();   // acquire: invalidate per-XCD caches before reading peers' data
  }
  __syncthreads();
}

__global__ __launch_bounds__(256, 2) void k_mega(
    const int* __restrict__ ids, const float* __restrict__ emb,
    const float* __restrict__ W, const float* __restrict__ bode,
    const float* __restrict__ w3c, const float* __restrict__ b3,
    const float* __restrict__ g3, const float* __restrict__ be3,
    const float* __restrict__ w4c, const float* __restrict__ b4,
    const float* __restrict__ g4, const float* __restrict__ be4,
    const float* __restrict__ w5c, const float* __restrict__ b5,
    const float* __restrict__ g5, const float* __restrict__ be5,
    const float* __restrict__ wc, const float* __restrict__ bc,
    float* __restrict__ out,
    float* __restrict__ Bm, float* __restrict__ N2,
    float* __restrict__ c1, float* __restrict__ c10,
    unsigned short* __restrict__ slab, unsigned* __restrict__ featbuf,
    unsigned* __restrict__ bar) {
  __shared__ alignas(16) unsigned short Xt[68 * 264];
  __shared__ int ids_s[68];
  const int tid = threadIdx.x;
  const int blk = blockIdx.x;

  // prep-phase LDS aliases (overwritten by Xt gather later)
  float* r1  = (float*)Xt;         // 256 floats
  float* r2  = r1 + 256;
  float* r3  = r1 + 512;
  float* red = r1 + 768;           // 4 floats

  // ---------------- stage 0: W-power chain -> B,c1 | conv repack + featbuf zero
  if (blk < 256) {
    const int i = blk;
    r1[tid] = W[i * 256 + tid];
    __syncthreads();
    const float v2 = dotcol(r1, W, tid);   // W^2[i][tid]
    r2[tid] = v2;
    __syncthreads();
    const float v3 = dotcol(r2, W, tid);   // W^3[i][tid]
    r3[tid] = v3;
    __syncthreads();
    const float v4 = dotcol(r3, W, tid);   // W^4[i][tid]
    const float w1 = r1[tid];
    Bm[i * 256 + tid] = 0.1f * w1 + 0.005f * v2
                      + (0.001f / 6.f) * v3 + (0.0001f / 24.f) * v4;
    const float q = 0.05f * w1 + (0.01f / 6.f) * v2 + (0.001f / 24.f) * v3;
    float val = bode[tid] * q;
#pragma unroll
    for (int off = 32; off > 0; off >>= 1) val += __shfl_down(val, off);
    if ((tid & 63) == 0) red[tid >> 6] = val;
    __syncthreads();
    if (tid == 0) c1[i] = 0.1f * (bode[i] + ((red[0] + red[1]) + (red[2] + red[3])));
  } else {
    const int base = (blk - 256) * 256 + tid;   // 0..65535
#pragma unroll
    for (int u = 0; u < 6; ++u) {
      int e = base + u * 65536;                 // covers 0..393215 = 12*32768
      int s = e >> 15, r = e & 32767, kd = r >> 7, o = r & 127;
      const float* w; int k, j;
      if (s < 3)      { w = w3c; k = 3; j = s; }
      else if (s < 7) { w = w4c; k = 4; j = s - 3; }
      else            { w = w5c; k = 5; j = s - 7; }
      float val = w[(o * 256 + kd) * k + j];    // w[o][d=kd][j], shape (128,256,k)
      int kc = kd >> 5, quad = (kd >> 3) & 3, q8 = kd & 7;
      slab[s * 32768 + ((kc * 4 + quad) * 128 + o) * 8 + q8] = f2bf(val);
    }
    if (base < 64 * 640) featbuf[base] = 0u;
  }
  gbar(bar, bar + 1);

  // ---------------- stage 1: N2 = I + 2B + B^2 | c2 (block 300, kept in LDS)
  if (blk < 256) {
    r1[tid] = Bm[blk * 256 + tid];
    __syncthreads();
    const float s = dotcol(r1, Bm, tid);
    N2[blk * 256 + tid] = ((blk == tid) ? 1.f : 0.f) + 2.f * r1[tid] + s;
  } else if (blk == 300) {
    r1[tid] = c1[tid];
    __syncthreads();
    // c2[j] = 2*c1[j] + sum_k c1[k]*B[j][k]
    const float acc = rowscan(r1, Bm + (size_t)tid * 256, 2.f * r1[tid]);
    __syncthreads();
    r1[tid] = acc;   // running c
    r2[tid] = acc;   // c2 (persists to stage 2)
    __syncthreads();
  }
  gbar(bar, bar + 1);

  // ---------------- stage 2: N10 row -> slab node scatter | c-chain -> c10
  if (blk < 256) {
    r1[tid] = N2[blk * 256 + tid];
    __syncthreads();
    float v = 0.f;
#pragma unroll 1
    for (int it = 0; it < 4; ++it) {
      v = dotcol(r1, N2, tid);
      __syncthreads();
      r1[tid] = v;
      __syncthreads();
    }
    // v = N10[o=blk][kd=tid] = P10[kd][o]
    const int o = blk, kd = tid;
    const int kc = kd >> 5, quad = (kd >> 3) & 3, q8 = kd & 7;
    slab[(12 + (o >> 7)) * 32768 + ((kc * 4 + quad) * 128 + (o & 127)) * 8 + q8] = f2bf(v);
  } else if (blk == 300) {
    // c_{k+2} = c_k @ M^2 + c2 ; (c@M^2)[j] = sum_k c[k]*N2[j][k]
#pragma unroll 1
    for (int it = 0; it < 4; ++it) {
      const float a = rowscan(r1, N2 + (size_t)tid * 256, r2[tid]);
      __syncthreads();
      r1[tid] = a;
      __syncthreads();
    }
    c10[tid] = r1[tid];
  }
  gbar(bar, bar + 1);

  // ---------------- main: conv+node GEMMs, 64 batches x 8 t-chunks ----------------
  const int b = blk >> 3;
  const int t0 = (blk & 7) * 64;
  const int lane = tid & 63;
  const int wave = tid >> 6;
  const int m15 = lane & 15;
  const int quad = lane >> 4;

  if (tid < 68) {
    int t = t0 + tid;
    ids_s[tid] = (t < 512) ? ids[b * 512 + t] : -1;
  }
  __syncthreads();

  // per-lane B-fragment base; frag(e,kc2,nt) = fb0 + e*8192 + kc2*4096 + nt*128
  const unsigned short* fb0 = slab + ((size_t)quad * 128 + wave * 2 * 16 + m15) * 8;
  bf16x8 fA[4], fB[4], fC[4], fD[4];   // [kc2*2+nt], 4-deep entry pipeline
#define LDFRAG(DST, EN)                                                         \
  {                                                                             \
    const unsigned short* p_ = fb0 + (EN) * 8192;                               \
    DST[0] = *(const bf16x8*)(p_);                                              \
    DST[1] = *(const bf16x8*)(p_ + 128);                                        \
    DST[2] = *(const bf16x8*)(p_ + 4096);                                       \
    DST[3] = *(const bf16x8*)(p_ + 4096 + 128);                                 \
  }
  LDFRAG(fA, 0) LDFRAG(fB, 1) LDFRAG(fC, 2) LDFRAG(fD, 3)

  // gather + fp32->bf16 X tile (overlaps the frag loads above)
  for (int i = tid; i < 68 * 64; i += 256) {
    int row = i >> 6, s4 = i & 63;
    uint2 v = make_uint2(0u, 0u);
    int id = ids_s[row];
    if (id >= 0) {
      const float4 f = *(const float4*)(emb + (size_t)id * 256 + s4 * 4);
      v.x = (unsigned)f2bf(f.x) | ((unsigned)f2bf(f.y) << 16);
      v.y = (unsigned)f2bf(f.z) | ((unsigned)f2bf(f.w) << 16);
    }
    *(uint2*)&Xt[row * 264 + s4 * 4] = v;
  }
  __syncthreads();  // Xt ready; no barriers in main loop

  f32x4 acc[4][2];
#pragma unroll
  for (int mt = 0; mt < 4; ++mt)
#pragma unroll
    for (int nt = 0; nt < 2; ++nt) acc[mt][nt] = (f32x4){0.f, 0.f, 0.f, 0.f};

#define ENTRY(KCQ, FR)                                                          \
  {                                                                             \
    _Pragma("unroll")                                                           \
    for (int kc2 = 0; kc2 < 2; ++kc2) {                                         \
      const int kd0 = ((KCQ) * 2 + kc2) * 32 + quad * 8;                        \
      bf16x8 af[4];                                                             \
      _Pragma("unroll")                                                         \
      for (int mt = 0; mt < 4; ++mt)                                            \
        af[mt] = *(const bf16x8*)&Xt[(shift + mt * 16 + m15) * 264 + kd0];      \
      _Pragma("unroll")                                                         \
      for (int mt = 0; mt < 4; ++mt) {                                          \
        acc[mt][0] = __builtin_amdgcn_mfma_f32_16x16x32_bf16(af[mt], FR[kc2 * 2 + 0], acc[mt][0], 0, 0, 0); \
        acc[mt][1] = __builtin_amdgcn_mfma_f32_16x16x32_bf16(af[mt], FR[kc2 * 2 + 1], acc[mt][1], 0, 0, 0); \
      }                                                                         \
    }                                                                           \
  }

  // entries e = eq*4 + j; slice = eq (same shift across a group); kcq = j.
  // epilogues land exactly at j=3 of eq = 2,6,11,12,13.
  for (int eq = 0; eq < 14; ++eq) {
    const int shift = (eq < 3) ? eq : (eq < 7) ? (eq - 3) : (eq < 12) ? (eq - 7) : 0;

    ENTRY(0, fA) if (eq < 13) LDFRAG(fA, (eq + 1) * 4 + 0)
    ENTRY(1, fB) if (eq < 13) LDFRAG(fB, (eq + 1) * 4 + 1)
    ENTRY(2, fC) if (eq < 13) LDFRAG(fC, (eq + 1) * 4 + 2)
    ENTRY(3, fD) if (eq < 13) LDFRAG(fD, (eq + 1) * 4 + 3)

    const int g = (eq == 2) ? 0 : (eq == 6) ? 1 : (eq == 11) ? 2
                : (eq == 12) ? 3 : (eq == 13) ? 4 : -1;
    if (g >= 0) {
      if (g < 3) {
        const int kk = g + 3;
        const float* bb  = (g == 0) ? b3 : (g == 1) ? b4 : b5;
        const float* gg  = (g == 0) ? g3 : (g == 1) ? g4 : g5;
        const float* bbe = (g == 0) ? be3 : (g == 1) ? be4 : be5;
        const int off = 256 + g * 128;     // feats: [node 256][p3 128][p4 128][p5 128]
        const int tmax = 512 - kk;
#pragma unroll
        for (int nt = 0; nt < 2; ++nt) {
          const int n = (wave * 2 + nt) * 16 + m15;
          const float sc = gg[n] * 0.9999950000375f;  // g * 1/sqrt(1+1e-5)
          const float sh = fmaf(sc, bb[n], bbe[n]);
          float mx = 0.f;  // relu floor doubles as init
#pragma unroll
          for (int mt = 0; mt < 4; ++mt)
#pragma unroll
            for (int r = 0; r < 4; ++r) {
              const int t = t0 + mt * 16 + quad * 4 + r;
              const float v = fmaf(sc, acc[mt][nt][r], sh);
              if (t <= tmax) mx = fmaxf(mx, v);
            }
          mx = fmaxf(mx, __shfl_xor(mx, 16));
          mx = fmaxf(mx, __shfl_xor(mx, 32));
          if (quad == 0) atomicMax(&featbuf[b * 640 + off + n], __float_as_uint(mx));
        }
      } else {
        const int base = (g == 3) ? 0 : 128;
#pragma unroll
        for (int nt = 0; nt < 2; ++nt) {
          const int n = (wave * 2 + nt) * 16 + m15;
          const float ct = c10[base + n];
          float mx = -3.4e38f;
#pragma unroll
          for (int mt = 0; mt < 4; ++mt)
#pragma unroll
            for (int r = 0; r < 4; ++r)
              mx = fmaxf(mx, acc[mt][nt][r] + ct);
          mx = fmaxf(mx, __shfl_xor(mx, 16));
          mx = fmaxf(mx, __shfl_xor(mx, 32));
          if (quad == 0) {
            unsigned bits = __float_as_uint(mx);
            unsigned key = (bits & 0x80000000u) ? ~bits : (bits | 0x80000000u);  // order-preserving
            atomicMax(&featbuf[b * 640 + base + n], key);
          }
        }
      }
#pragma unroll
      for (int mt = 0; mt < 4; ++mt)
#pragma unroll
        for (int nt = 0; nt < 2; ++nt) acc[mt][nt] = (f32x4){0.f, 0.f, 0.f, 0.f};
    }
  }
#undef ENTRY
#undef LDFRAG

  // ---------------- finisher: classifier (blocks 0-63, wave 0) ----------------
  gbar(bar, bar + 1);
  if (blk < 64 && tid < 64) {
    float vv[10];
#pragma unroll
    for (int it = 0; it < 10; ++it) {           // 10 independent loads, batched
      unsigned u = featbuf[blk * 640 + it * 64 + tid];
      if (it < 4)  // f < 256: node keys are order-preserving-mapped
        vv[it] = (u & 0x80000000u) ? __uint_as_float(u ^ 0x80000000u)
                                   : __uint_as_float(~u);
      else
        vv[it] = __uint_as_float(u);
    }
    float p[10];
#pragma unroll
    for (int c = 0; c < 10; ++c) p[c] = 0.f;
#pragma unroll
    for (int it = 0; it < 10; ++it)
#pragma unroll
      for (int c = 0; c < 10; ++c)
        p[c] = fmaf(vv[it], wc[c * 640 + it * 64 + tid], p[c]);
#pragma unroll
    for (int c = 0; c < 10; ++c) {
      float s = p[c];
#pragma unroll
      for (int off = 32; off > 0; off >>= 1) s += __shfl_down(s, off);
      if (tid == 0) out[blk * 10 + c] = s + bc[c];
    }
  }
}

// ---------------- launcher ----------------
extern "C" void kernel_launch(void* const* d_in, const int* in_sizes, int n_in,
                              void* d_out, int out_size, void* d_ws, size_t ws_size,
                              hipStream_t stream) {
  (void)in_sizes; (void)n_in; (void)out_size; (void)ws_size;
  const int*   ids  = (const int*)d_in[0];
  const float* emb  = (const float*)d_in[1];
  const float* W    = (const float*)d_in[2];
  const float* bode = (const float*)d_in[3];
  const float* w3   = (const float*)d_in[4];
  const float* b3   = (const float*)d_in[5];
  const float* g3   = (const float*)d_in[6];
  const float* be3  = (const float*)d_in[7];
  const float* w4   = (const float*)d_in[8];
  const float* b4   = (const float*)d_in[9];
  const float* g4   = (const float*)d_in[10];
  const float* be4  = (const float*)d_in[11];
  const float* w5   = (const float*)d_in[12];
  const float* b5   = (const float*)d_in[13];
  const float* g5   = (const float*)d_in[14];
  const float* be5  = (const float*)d_in[15];
  const float* wc   = (const float*)d_in[16];
  const float* bc   = (const float*)d_in[17];
  float* out = (float*)d_out;

  float* wsf = (float*)d_ws;
  // ws layout (floats): B 0 | N2 65536 | c1 131072 | c10 131328 |
  // slab 131584 (14*32768 bf16 = 229376 floats) | featbuf 360960 (40960) | bar 401920 (2)
  float* Bm  = wsf;
  float* N2  = wsf + 65536;
  float* c1  = wsf + 131072;
  float* c10 = wsf + 131328;
  unsigned short* slab = (unsigned short*)(wsf + 131584);
  unsigned* featbuf = (unsigned*)(wsf + 360960);
  unsigned* bar     = (unsigned*)(wsf + 401920);

  hipMemsetAsync(bar, 0, 8, stream);   // cnt, flag (barrier is replay-safe anyway)
  hipLaunchKernelGGL(k_mega, dim3(512), dim3(256), 0, stream,
                     ids, emb, W, bode,
                     w3, b3, g3, be3, w4, b4, g4, be4, w5, b5, g5, be5,
                     wc, bc, out, Bm, N2, c1, c10, slab, featbuf, bar);
}

// Round 7
// 377.358 us; speedup vs baseline: 1.1295x; 1.1295x over previous
//
#include <hip/hip_runtime.h>

// B=64, S=512, D=256, VOCAB=50000, NC=10, N_STEPS=10 (h=0.1), BN eval.
// z_final = z0 @ P10 + c10, P10 = M^10, M = Taylor4(exp(hA)), A = W^T.
// Transpose trick: M = N^T, N = I + B, B = 0.1W + 0.005W^2 + (1e-3/6)W^3 + (1e-4/24)W^4,
// so P10 = (N^10)^T; the transpose is absorbed into the slab fragment scatter.
//
// LESSONS (rounds 1-6):
//  - Dispatch boundaries ~17-30us each. cg grid.sync ~110us. Full hand-rolled
//    fence barriers ~70us each (R6: __threadfence invalidation thrash, FETCH
//    20->27GB, 310us idle). All three sync styles measured and rejected.
//  - THIS ROUND: producer->consumer COUNTER GATES, no barriers, no threadfence.
//    Producers write B/N2/slab-node/c10 with agent-scope atomic stores (bypass
//    L2 -> coherence point), signal via RELEASE fetch_add; consumers ACQUIRE-
//    spin then use plain cached loads. Safe because no consumer touches those
//    lines pre-gate (dispatch-start invalidate => no stale copies), and ws
//    values are replay-idempotent. 2 queue ops total: 32B memset + kernel.
//  - k_main body: R6's depth-4 B-frag register pipeline (passed correctness),
//    B-frags direct from L2-resident slab (R5: LDS B-staging was the 17.5%
//    MfmaUtil bottleneck). Finisher: done-counter + batched agent atomic
//    loads (R4's serialized-atomic 145us tail avoided).

typedef short bf16x8 __attribute__((ext_vector_type(8)));
typedef float f32x4 __attribute__((ext_vector_type(4)));

__device__ __forceinline__ unsigned short f2bf(float f) {
  unsigned u = __float_as_uint(f);
  u += 0x7FFFu + ((u >> 16) & 1u);   // RNE; inputs are normal floats
  return (unsigned short)(u >> 16);
}

// agent-scope (bypass-L2) stores: land at the coherence point
__device__ __forceinline__ void gstf(float* p, float v) {
  __hip_atomic_store(p, v, __ATOMIC_RELAXED, __HIP_MEMORY_SCOPE_AGENT);
}
__device__ __forceinline__ void gst16(unsigned short* p, unsigned short v) {
  __hip_atomic_store(p, v, __ATOMIC_RELAXED, __HIP_MEMORY_SCOPE_AGENT);
}
__device__ __forceinline__ void gstu(unsigned* p, unsigned v) {
  __hip_atomic_store(p, v, __ATOMIC_RELAXED, __HIP_MEMORY_SCOPE_AGENT);
}
// producer signal: __syncthreads (drains vmcnt per-thread) must precede; tid0 adds.
__device__ __forceinline__ void signal(unsigned* c) {
  __hip_atomic_fetch_add(c, 1u, __ATOMIC_RELEASE, __HIP_MEMORY_SCOPE_AGENT);
}
// consumer gate: acquire-spin on tid0, then block-wide sync
__device__ __forceinline__ void gwait(unsigned* c, unsigned tgt) {
  __syncthreads();
  if (threadIdx.x == 0)
    while (__hip_atomic_load(c, __ATOMIC_ACQUIRE, __HIP_MEMORY_SCOPE_AGENT) < tgt)
      __builtin_amdgcn_s_sleep(4);
  __syncthreads();
}

// acc_j = sum_k xrow[k] * Y[k][tid]; xrow in LDS, Y global, coalesced.
__device__ __forceinline__ float dotcol(const float* __restrict__ xrow,
                                        const float* __restrict__ Y, int tid) {
  float a0 = 0.f, a1 = 0.f, a2 = 0.f, a3 = 0.f;
#pragma unroll 4
  for (int k = 0; k < 256; k += 16) {
    float bv[16];
#pragma unroll
    for (int u = 0; u < 16; ++u) bv[u] = Y[(k + u) * 256 + tid];
#pragma unroll
    for (int u = 0; u < 16; u += 4) {
      a0 = fmaf(xrow[k + u + 0], bv[u + 0], a0);
      a1 = fmaf(xrow[k + u + 1], bv[u + 1], a1);
      a2 = fmaf(xrow[k + u + 2], bv[u + 2], a2);
      a3 = fmaf(xrow[k + u + 3], bv[u + 3], a3);
    }
  }
  return (a0 + a1) + (a2 + a3);
}

// init + sum_k cvec[k] * row[k]; cvec in LDS, row = one global row (per-thread).
__device__ __forceinline__ float rowscan(const float* __restrict__ cvec,
                                         const float* __restrict__ row, float init) {
  float a0 = init, a1 = 0.f, a2 = 0.f, a3 = 0.f;
#pragma unroll 4
  for (int k = 0; k < 256; k += 16) {
    float bv[16];
#pragma unroll
    for (int u = 0; u < 16; ++u) bv[u] = row[k + u];
#pragma unroll
    for (int u = 0; u < 16; u += 4) {
      a0 = fmaf(cvec[k + u + 0], bv[u + 0], a0);
      a1 = fmaf(cvec[k + u + 1], bv[u + 1], a1);
      a2 = fmaf(cvec[k + u + 2], bv[u + 2], a2);
      a3 = fmaf(cvec[k + u + 3], bv[u + 3], a3);
    }
  }
  return (a0 + a1) + (a2 + a3);
}

// bar: [0]=cntB(256) [1]=cntR(256) [2]=cntN2(256) [3]=cntNode(257) [4]=done(512)
__global__ __launch_bounds__(256, 2) void k_mega(
    const int* __restrict__ ids, const float* __restrict__ emb,
    const float* __restrict__ W, const float* __restrict__ bode,
    const float* __restrict__ w3c, const float* __restrict__ b3,
    const float* __restrict__ g3, const float* __restrict__ be3,
    const float* __restrict__ w4c, const float* __restrict__ b4,
    const float* __restrict__ g4, const float* __restrict__ be4,
    const float* __restrict__ w5c, const float* __restrict__ b5,
    const float* __restrict__ g5, const float* __restrict__ be5,
    const float* __restrict__ wc, const float* __restrict__ bc,
    float* __restrict__ out,
    float* __restrict__ Bm, float* __restrict__ N2,
    float* __restrict__ c1, float* __restrict__ c10,
    unsigned short* __restrict__ slab, unsigned* __restrict__ featbuf,
    unsigned* __restrict__ bar) {
  __shared__ alignas(16) unsigned short Xt[68 * 264];
  __shared__ int ids_s[68];
  __shared__ unsigned lastf;
  const int tid = threadIdx.x;
  const int blk = blockIdx.x;

  // prep-phase LDS aliases (overwritten by Xt gather later)
  float* r1  = (float*)Xt;         // 256 floats
  float* r2  = r1 + 256;
  float* r3  = r1 + 512;
  float* red = r1 + 768;

  if (blk < 256) {
    // ---- P0: W-power row chain -> B row + c1[i] (agent stores)
    const int i = blk;
    r1[tid] = W[i * 256 + tid];
    __syncthreads();
    const float v2 = dotcol(r1, W, tid);   // W^2[i][tid]
    r2[tid] = v2;
    __syncthreads();
    const float v3 = dotcol(r2, W, tid);   // W^3[i][tid]
    r3[tid] = v3;
    __syncthreads();
    const float v4 = dotcol(r3, W, tid);   // W^4[i][tid]
    const float w1 = r1[tid];
    gstf(&Bm[i * 256 + tid], 0.1f * w1 + 0.005f * v2
                           + (0.001f / 6.f) * v3 + (0.0001f / 24.f) * v4);
    const float q = 0.05f * w1 + (0.01f / 6.f) * v2 + (0.001f / 24.f) * v3;
    float val = bode[tid] * q;
#pragma unroll
    for (int off = 32; off > 0; off >>= 1) val += __shfl_down(val, off);
    if ((tid & 63) == 0) red[tid >> 6] = val;
    __syncthreads();
    if (tid == 0) {
      gstf(&c1[i], 0.1f * (bode[i] + ((red[0] + red[1]) + (red[2] + red[3]))));
      signal(&bar[0]);   // B row + c1[i] visible (syncthreads drained this block's stores)
    }

    // ---- P1: N2 row (needs full B)
    gwait(&bar[0], 256);
    r1[tid] = Bm[blk * 256 + tid];
    __syncthreads();
    const float s2 = dotcol(r1, Bm, tid);
    gstf(&N2[blk * 256 + tid], ((blk == tid) ? 1.f : 0.f) + 2.f * r1[tid] + s2);
    __syncthreads();
    if (tid == 0) signal(&bar[2]);

    // ---- P2: N10 row = N2[i] @ (N2)^4 -> slab node scatter
    gwait(&bar[2], 256);
    r1[tid] = N2[blk * 256 + tid];
    __syncthreads();
    float v = 0.f;
#pragma unroll 1
    for (int it = 0; it < 4; ++it) {
      v = dotcol(r1, N2, tid);
      __syncthreads();
      r1[tid] = v;
      __syncthreads();
    }
    // v = N10[o=blk][kd=tid] = P10[kd][o]
    {
      const int o = blk, kd = tid;
      const int kc = kd >> 5, quad = (kd >> 3) & 3, q8 = kd & 7;
      gst16(&slab[(12 + (o >> 7)) * 32768 + ((kc * 4 + quad) * 128 + (o & 127)) * 8 + q8],
            f2bf(v));
    }
    __syncthreads();
    if (tid == 0) signal(&bar[3]);
  } else {
    // ---- repack: 6 elements/thread + featbuf zero (agent stores)
    const int base = (blk - 256) * 256 + tid;   // 0..65535
#pragma unroll
    for (int u = 0; u < 6; ++u) {
      int e = base + u * 65536;                 // covers 0..393215 = 12*32768
      int s = e >> 15, r = e & 32767, kd = r >> 7, o = r & 127;
      const float* w; int k, j;
      if (s < 3)      { w = w3c; k = 3; j = s; }
      else if (s < 7) { w = w4c; k = 4; j = s - 3; }
      else            { w = w5c; k = 5; j = s - 7; }
      float val = w[(o * 256 + kd) * k + j];    // w[o][d=kd][j], shape (128,256,k)
      int kc = kd >> 5, quad = (kd >> 3) & 3, q8 = kd & 7;
      gst16(&slab[s * 32768 + ((kc * 4 + quad) * 128 + o) * 8 + q8], f2bf(val));
    }
    if (base < 64 * 640) gstu(&featbuf[base], 0u);
    __syncthreads();
    if (tid == 0) signal(&bar[1]);

    if (blk == 256) {
      // ---- c-chain: c2 = 2c1 + c1.B-rows; 4x: c <- c.(N2)-rows + c2 -> c10
      gwait(&bar[0], 256);
      r1[tid] = c1[tid];
      __syncthreads();
      const float acc = rowscan(r1, Bm + (size_t)tid * 256, 2.f * r1[tid]);
      __syncthreads();
      r1[tid] = acc; r2[tid] = acc;
      __syncthreads();
      gwait(&bar[2], 256);
#pragma unroll 1
      for (int it = 0; it < 4; ++it) {
        const float a = rowscan(r1, N2 + (size_t)tid * 256, r2[tid]);
        __syncthreads();
        r1[tid] = a;
        __syncthreads();
      }
      gstf(&c10[tid], r1[tid]);
      __syncthreads();
      if (tid == 0) signal(&bar[3]);
    }
  }

  // ---------------- main: conv+node GEMMs, 64 batches x 8 t-chunks ----------------
  const int b = blk >> 3;
  const int t0 = (blk & 7) * 64;
  const int lane = tid & 63;
  const int wave = tid >> 6;
  const int m15 = lane & 15;
  const int quad = lane >> 4;

  __syncthreads();   // done with prep LDS aliases
  if (tid < 68) {
    int t = t0 + tid;
    ids_s[tid] = (t < 512) ? ids[b * 512 + t] : -1;
  }
  __syncthreads();
  // gather + fp32->bf16 X tile (rows beyond S zero-filled)
  for (int i = tid; i < 68 * 64; i += 256) {
    int row = i >> 6, s4 = i & 63;
    uint2 v = make_uint2(0u, 0u);
    int id = ids_s[row];
    if (id >= 0) {
      const float4 f = *(const float4*)(emb + (size_t)id * 256 + s4 * 4);
      v.x = (unsigned)f2bf(f.x) | ((unsigned)f2bf(f.y) << 16);
      v.y = (unsigned)f2bf(f.z) | ((unsigned)f2bf(f.w) << 16);
    }
    *(uint2*)&Xt[row * 264 + s4 * 4] = v;
  }
  gwait(&bar[1], 256);   // conv slab ready (includes Xt sync)

  // per-lane B-fragment base; frag(e,kc2,nt) = fb0 + e*8192 + kc2*4096 + nt*128
  const unsigned short* fb0 = slab + ((size_t)quad * 128 + wave * 2 * 16 + m15) * 8;
  bf16x8 fA[4], fB[4], fC[4], fD[4];   // [kc2*2+nt], 4-deep entry pipeline
#define LDFRAG(DST, EN)                                                         \
  {                                                                             \
    const unsigned short* p_ = fb0 + (EN) * 8192;                               \
    DST[0] = *(const bf16x8*)(p_);                                              \
    DST[1] = *(const bf16x8*)(p_ + 128);                                        \
    DST[2] = *(const bf16x8*)(p_ + 4096);                                       \
    DST[3] = *(const bf16x8*)(p_ + 4096 + 128);                                 \
  }
  LDFRAG(fA, 0) LDFRAG(fB, 1) LDFRAG(fC, 2) LDFRAG(fD, 3)

  f32x4 acc[4][2];
#pragma unroll
  for (int mt = 0; mt < 4; ++mt)
#pragma unroll
    for (int nt = 0; nt < 2; ++nt) acc[mt][nt] = (f32x4){0.f, 0.f, 0.f, 0.f};

#define ENTRY(KCQ, FR)                                                          \
  {                                                                             \
    _Pragma("unroll")                                                           \
    for (int kc2 = 0; kc2 < 2; ++kc2) {                                         \
      const int kd0 = ((KCQ) * 2 + kc2) * 32 + quad * 8;                        \
      bf16x8 af[4];                                                             \
      _Pragma("unroll")                                                         \
      for (int mt = 0; mt < 4; ++mt)                                            \
        af[mt] = *(const bf16x8*)&Xt[(shift + mt * 16 + m15) * 264 + kd0];      \
      _Pragma("unroll")                                                         \
      for (int mt = 0; mt < 4; ++mt) {                                          \
        acc[mt][0] = __builtin_amdgcn_mfma_f32_16x16x32_bf16(af[mt], FR[kc2 * 2 + 0], acc[mt][0], 0, 0, 0); \
        acc[mt][1] = __builtin_amdgcn_mfma_f32_16x16x32_bf16(af[mt], FR[kc2 * 2 + 1], acc[mt][1], 0, 0, 0); \
      }                                                                         \
    }                                                                           \
  }

  // entries e = eq*4 + j; slice = eq; kcq = j. Node entries (eq 12,13) are
  // prefetched during eq 11 -> gate on cntNode at eq==11.
  for (int eq = 0; eq < 14; ++eq) {
    if (eq == 11) gwait(&bar[3], 257);
    const int shift = (eq < 3) ? eq : (eq < 7) ? (eq - 3) : (eq < 12) ? (eq - 7) : 0;

    ENTRY(0, fA) if (eq < 13) LDFRAG(fA, (eq + 1) * 4 + 0)
    ENTRY(1, fB) if (eq < 13) LDFRAG(fB, (eq + 1) * 4 + 1)
    ENTRY(2, fC) if (eq < 13) LDFRAG(fC, (eq + 1) * 4 + 2)
    ENTRY(3, fD) if (eq < 13) LDFRAG(fD, (eq + 1) * 4 + 3)

    const int g = (eq == 2) ? 0 : (eq == 6) ? 1 : (eq == 11) ? 2
                : (eq == 12) ? 3 : (eq == 13) ? 4 : -1;
    if (g >= 0) {
      if (g < 3) {
        const int kk = g + 3;
        const float* bb  = (g == 0) ? b3 : (g == 1) ? b4 : b5;
        const float* gg  = (g == 0) ? g3 : (g == 1) ? g4 : g5;
        const float* bbe = (g == 0) ? be3 : (g == 1) ? be4 : be5;
        const int off = 256 + g * 128;     // feats: [node 256][p3 128][p4 128][p5 128]
        const int tmax = 512 - kk;
#pragma unroll
        for (int nt = 0; nt < 2; ++nt) {
          const int n = (wave * 2 + nt) * 16 + m15;
          const float sc = gg[n] * 0.9999950000375f;  // g * 1/sqrt(1+1e-5)
          const float sh = fmaf(sc, bb[n], bbe[n]);
          float mx = 0.f;  // relu floor doubles as init
#pragma unroll
          for (int mt = 0; mt < 4; ++mt)
#pragma unroll
            for (int r = 0; r < 4; ++r) {
              const int t = t0 + mt * 16 + quad * 4 + r;
              const float v = fmaf(sc, acc[mt][nt][r], sh);
              if (t <= tmax) mx = fmaxf(mx, v);
            }
          mx = fmaxf(mx, __shfl_xor(mx, 16));
          mx = fmaxf(mx, __shfl_xor(mx, 32));
          if (quad == 0) atomicMax(&featbuf[b * 640 + off + n], __float_as_uint(mx));
        }
      } else {
        const int base = (g == 3) ? 0 : 128;
#pragma unroll
        for (int nt = 0; nt < 2; ++nt) {
          const int n = (wave * 2 + nt) * 16 + m15;
          const float ct = c10[base + n];
          float mx = -3.4e38f;
#pragma unroll
          for (int mt = 0; mt < 4; ++mt)
#pragma unroll
            for (int r = 0; r < 4; ++r)
              mx = fmaxf(mx, acc[mt][nt][r] + ct);
          mx = fmaxf(mx, __shfl_xor(mx, 16));
          mx = fmaxf(mx, __shfl_xor(mx, 32));
          if (quad == 0) {
            unsigned bits = __float_as_uint(mx);
            unsigned key = (bits & 0x80000000u) ? ~bits : (bits | 0x80000000u);  // order-preserving
            atomicMax(&featbuf[b * 640 + base + n], key);
          }
        }
      }
#pragma unroll
      for (int mt = 0; mt < 4; ++mt)
#pragma unroll
        for (int nt = 0; nt < 2; ++nt) acc[mt][nt] = (f32x4){0.f, 0.f, 0.f, 0.f};
    }
  }
#undef ENTRY
#undef LDFRAG

  // ---------------- finisher: last block computes the classifier ----------------
  __syncthreads();   // drain this block's featbuf atomics (vmcnt) before done-add
  if (tid == 0)
    lastf = __hip_atomic_fetch_add(&bar[4], 1u, __ATOMIC_ACQ_REL, __HIP_MEMORY_SCOPE_AGENT);
  __syncthreads();
  if (lastf == 511u) {
    // 4 waves x 16 batches; per batch: 10 independent agent loads/lane, pipelined
#pragma unroll 2
    for (int bi = 0; bi < 16; ++bi) {
      const int bq = wave * 16 + bi;
      unsigned u[10];
#pragma unroll
      for (int it = 0; it < 10; ++it)
        u[it] = __hip_atomic_load(&featbuf[bq * 640 + it * 64 + lane],
                                  __ATOMIC_RELAXED, __HIP_MEMORY_SCOPE_AGENT);
      float p[10];
#pragma unroll
      for (int c = 0; c < 10; ++c) p[c] = 0.f;
#pragma unroll
      for (int it = 0; it < 10; ++it) {
        float v;
        if (it < 4)   // node keys: order-preserving map
          v = (u[it] & 0x80000000u) ? __uint_as_float(u[it] ^ 0x80000000u)
                                    : __uint_as_float(~u[it]);
        else
          v = __uint_as_float(u[it]);
#pragma unroll
        for (int c = 0; c < 10; ++c)
          p[c] = fmaf(v, wc[c * 640 + it * 64 + lane], p[c]);
      }
#pragma unroll
      for (int c = 0; c < 10; ++c) {
        float s = p[c];
#pragma unroll
        for (int off = 32; off > 0; off >>= 1) s += __shfl_down(s, off);
        if (lane == 0) out[bq * 10 + c] = s + bc[c];
      }
    }
  }
}

// ---------------- launcher ----------------
extern "C" void kernel_launch(void* const* d_in, const int* in_sizes, int n_in,
                              void* d_out, int out_size, void* d_ws, size_t ws_size,
                              hipStream_t stream) {
  (void)in_sizes; (void)n_in; (void)out_size; (void)ws_size;
  const int*   ids  = (const int*)d_in[0];
  const float* emb  = (const float*)d_in[1];
  const float* W    = (const float*)d_in[2];
  const float* bode = (const float*)d_in[3];
  const float* w3   = (const float*)d_in[4];
  const float* b3   = (const float*)d_in[5];
  const float* g3   = (const float*)d_in[6];
  const float* be3  = (const float*)d_in[7];
  const float* w4   = (const float*)d_in[8];
  const float* b4   = (const float*)d_in[9];
  const float* g4   = (const float*)d_in[10];
  const float* be4  = (const float*)d_in[11];
  const float* w5   = (const float*)d_in[12];
  const float* b5   = (const float*)d_in[13];
  const float* g5   = (const float*)d_in[14];
  const float* be5  = (const float*)d_in[15];
  const float* wc   = (const float*)d_in[16];
  const float* bc   = (const float*)d_in[17];
  float* out = (float*)d_out;

  float* wsf = (float*)d_ws;
  // ws layout (floats): B 0 | N2 65536 | c1 131072 | c10 131328 |
  // slab 131584 (14*32768 bf16 = 229376 floats) | featbuf 360960 (40960) | bar 401920 (8)
  float* Bm  = wsf;
  float* N2  = wsf + 65536;
  float* c1  = wsf + 131072;
  float* c10 = wsf + 131328;
  unsigned short* slab = (unsigned short*)(wsf + 131584);
  unsigned* featbuf = (unsigned*)(wsf + 360960);
  unsigned* bar     = (unsigned*)(wsf + 401920);

  hipMemsetAsync(bar, 0, 32, stream);
  hipLaunchKernelGGL(k_mega, dim3(512), dim3(256), 0, stream,
                     ids, emb, W, bode,
                     w3, b3, g3, be3, w4, b4, g4, be4, w5, b5, g5, be5,
                     wc, bc, out, Bm, N2, c1, c10, slab, featbuf, bar);
}

// Round 8
// 242.728 us; speedup vs baseline: 1.7560x; 1.5547x over previous
//
#include <hip/hip_runtime.h>

// B=64, S=512, D=256, VOCAB=50000, NC=10, N_STEPS=10 (h=0.1), BN eval.
// z_final = z0 @ P10 + c10, P10 = M^10, M = Taylor4(exp(hA)), A = W^T.
// Transpose trick: M = N^T, N = I + B, B = 0.1W + 0.005W^2 + (1e-3/6)W^3 + (1e-4/24)W^4,
// so P10 = (N^10)^T; the transpose is absorbed into the slab fragment scatter.
//
// LESSONS (R1-R7):
//  - All intra-kernel global sync styles cost 70-110us/event on MI355X
//    (cg grid.sync 110, fence barrier 70, atomic-poll gates ~100: polling
//    serializes at the coherence point and delays the producer's signal).
//    Megakernels rejected; multi-dispatch boundaries are only ~4-5us.
//  - R5's 223us = 47.5 k_main + ~170 prep: prep = 8 SERIAL row-GEMM passes
//    x ~20us each (1 block/CU, 4 waves, latency-bound).
//  - THIS ROUND: per-pass latency attacked with 1024-thread K-split blocks
//    (64-load chains, 16 waves/block, LDS combine) ~2-3us/pass; serial depth
//    8 -> 6 (W4 chained off W3 with Y=W fixed; B,c1 fused into pass-1 epilogue);
//    c-chain as coalesced wave-per-row. k_main: depth-4 B-frag pipeline
//    (validated R6/R7).

typedef short bf16x8 __attribute__((ext_vector_type(8)));
typedef float f32x4 __attribute__((ext_vector_type(4)));

__device__ __forceinline__ unsigned short f2bf(float f) {
  unsigned u = __float_as_uint(f);
  u += 0x7FFFu + ((u >> 16) & 1u);   // RNE; inputs are normal floats
  return (unsigned short)(u >> 16);
}

// One row-GEMM pass with 1024 threads: dst_row = src_row @ Y.
// Thread t: col c = t&255, K-group g = t>>8 (64 rows of Y each).
// dst/src are LDS float[256] (dst may alias src); part is LDS float[1024].
__device__ __forceinline__ void rstep(float* __restrict__ dst, const float* __restrict__ src,
                                      const float* __restrict__ Y, float* __restrict__ part,
                                      int t) {
  const int c = t & 255, g = t >> 8;
  const float* Yc = Y + (size_t)(g * 64) * 256 + c;
  const float* sg = src + g * 64;
  float a0 = 0.f, a1 = 0.f, a2 = 0.f, a3 = 0.f;
#pragma unroll 4
  for (int u = 0; u < 64; u += 16) {
    float bv[16];
#pragma unroll
    for (int v = 0; v < 16; ++v) bv[v] = Yc[(u + v) * 256];
#pragma unroll
    for (int v = 0; v < 16; v += 4) {
      a0 = fmaf(sg[u + v + 0], bv[v + 0], a0);
      a1 = fmaf(sg[u + v + 1], bv[v + 1], a1);
      a2 = fmaf(sg[u + v + 2], bv[v + 2], a2);
      a3 = fmaf(sg[u + v + 3], bv[v + 3], a3);
    }
  }
  part[t] = (a0 + a1) + (a2 + a3);
  __syncthreads();
  if (t < 256) dst[t] = (part[t] + part[t + 256]) + (part[t + 512] + part[t + 768]);
  __syncthreads();
}

// ---- d1: blocks 0-255: row chain W->W2->W3->W4 (Y=W fixed) -> B row, c1[i].
//          blocks 256-351: conv repack (4 elems/thread) + featbuf zero.
__global__ __launch_bounds__(1024) void k_prep1(
    const float* __restrict__ W, const float* __restrict__ bode,
    const float* __restrict__ w3c, const float* __restrict__ w4c, const float* __restrict__ w5c,
    float* __restrict__ Bm, float* __restrict__ c1,
    unsigned short* __restrict__ slab, unsigned* __restrict__ featbuf) {
  __shared__ float part[1024], ra[256], rb[256], rc[256], rd[256], red[4];
  const int t = threadIdx.x, blk = blockIdx.x;
  if (blk < 256) {
    const int i = blk;
    if (t < 256) ra[t] = W[i * 256 + t];
    __syncthreads();
    rstep(rb, ra, W, part, t);   // W2 row
    rstep(rc, rb, W, part, t);   // W3 row
    rstep(rd, rc, W, part, t);   // W4 row
    if (t < 256) {
      Bm[i * 256 + t] = 0.1f * ra[t] + 0.005f * rb[t]
                      + (0.001f / 6.f) * rc[t] + (0.0001f / 24.f) * rd[t];
      const float q = 0.05f * ra[t] + (0.01f / 6.f) * rb[t] + (0.001f / 24.f) * rc[t];
      float val = bode[t] * q;
#pragma unroll
      for (int off = 32; off > 0; off >>= 1) val += __shfl_down(val, off);
      if ((t & 63) == 0) red[t >> 6] = val;
    }
    __syncthreads();
    if (t == 0) c1[i] = 0.1f * (bode[i] + ((red[0] + red[1]) + (red[2] + red[3])));
  } else {
    const int base = (blk - 256) * 1024 + t;    // 0..98303
#pragma unroll
    for (int u = 0; u < 4; ++u) {
      int e = base + u * 98304;                 // covers 0..393215 = 12*32768
      int s = e >> 15, r = e & 32767, kd = r >> 7, o = r & 127;
      const float* w; int k, j;
      if (s < 3)      { w = w3c; k = 3; j = s; }
      else if (s < 7) { w = w4c; k = 4; j = s - 3; }
      else            { w = w5c; k = 5; j = s - 7; }
      float val = w[(o * 256 + kd) * k + j];    // w[o][d=kd][j], shape (128,256,k)
      int kc = kd >> 5, quad = (kd >> 3) & 3, q8 = kd & 7;
      slab[s * 32768 + ((kc * 4 + quad) * 128 + o) * 8 + q8] = f2bf(val);
    }
    if (base < 64 * 640) featbuf[base] = 0u;
  }
}

// ---- d2: N2 = I + 2B + B^2 (one pass, Y=B)
__global__ __launch_bounds__(1024) void k_prep2(const float* __restrict__ Bm,
                                                float* __restrict__ N2) {
  __shared__ float part[1024], ra[256], rb[256];
  const int t = threadIdx.x, i = blockIdx.x;
  if (t < 256) ra[t] = Bm[i * 256 + t];
  __syncthreads();
  rstep(rb, ra, Bm, part, t);
  if (t < 256) N2[i * 256 + t] = ((i == t) ? 1.f : 0.f) + 2.f * ra[t] + rb[t];
}

// ---- d3: blocks 0-255: row chain N2[i] x (N2)^4 = N10[i] -> slab node scatter.
//          block 256: c-chain (coalesced wave-per-row): c2 then 4x (c <- c@M2 + c2).
__global__ __launch_bounds__(1024) void k_prep3(
    const float* __restrict__ Bm, const float* __restrict__ N2,
    const float* __restrict__ c1, float* __restrict__ c10,
    unsigned short* __restrict__ slab) {
  __shared__ float part[1024], ra[256], rb[256], rc[256], rd[256];
  const int t = threadIdx.x, blk = blockIdx.x;
  if (blk < 256) {
    if (t < 256) ra[t] = N2[blk * 256 + t];
    __syncthreads();
    rstep(ra, ra, N2, part, t);
    rstep(ra, ra, N2, part, t);
    rstep(ra, ra, N2, part, t);
    rstep(ra, ra, N2, part, t);
    if (t < 256) {
      // ra[t] = N10[o=blk][kd=t] = P10[kd][o]
      const int o = blk, kd = t;
      const int kc = kd >> 5, quad = (kd >> 3) & 3, q8 = kd & 7;
      slab[(12 + (o >> 7)) * 32768 + ((kc * 4 + quad) * 128 + (o & 127)) * 8 + q8] = f2bf(ra[t]);
    }
  } else {
    // c-chain: 16 waves x 16 rows each, 4-row chunks (16 coalesced loads in flight)
    const int w = t >> 6, lane = t & 63;
    if (t < 256) { ra[t] = c1[t]; rd[t] = 2.f * c1[t]; }
    __syncthreads();
    // cstep: dst[j] = add2[j] + sum_k src[k]*Ymat[j][k]
#define CSTEP(SRC, YMAT, ADD2, DST)                                             \
    {                                                                           \
      for (int r0i = 0; r0i < 16; r0i += 4) {                                   \
        float bv[4][4];                                                         \
        _Pragma("unroll")                                                       \
        for (int rr = 0; rr < 4; ++rr) {                                        \
          const int j = w * 16 + r0i + rr;                                      \
          _Pragma("unroll")                                                     \
          for (int q = 0; q < 4; ++q) bv[rr][q] = YMAT[j * 256 + lane + 64 * q];\
        }                                                                       \
        _Pragma("unroll")                                                       \
        for (int rr = 0; rr < 4; ++rr) {                                        \
          const int j = w * 16 + r0i + rr;                                      \
          float v = 0.f;                                                        \
          _Pragma("unroll")                                                     \
          for (int q = 0; q < 4; ++q) v = fmaf(SRC[lane + 64 * q], bv[rr][q], v);\
          _Pragma("unroll")                                                     \
          for (int off = 32; off > 0; off >>= 1) v += __shfl_down(v, off);      \
          if (lane == 0) DST[j] = ADD2[j] + v;                                  \
        }                                                                       \
      }                                                                         \
      __syncthreads();                                                          \
    }
    CSTEP(ra, Bm, rd, rb)   // rb = c2 = 2c1 + c1.B-rows
    CSTEP(rb, N2, rb, rc)   // rc = c4
    CSTEP(rc, N2, rb, rd)   // rd = c6
    CSTEP(rd, N2, rb, rc)   // rc = c8
    CSTEP(rc, N2, rb, rd)   // rd = c10
#undef CSTEP
    if (t < 256) c10[t] = rd[t];
  }
}

// ---------------- fused main kernel (R5 structure + R6/R7 depth-4 pipeline) ----------------
// grid 512 = 64 batches x 8 t-chunks of 64. 256 threads = 4 waves.
// LDS: only the X tile. B-fragments read per-wave directly from the
// L2-resident slab with a 4-deep register pipeline; no barriers in main loop.

__global__ __launch_bounds__(256, 2) void k_main(
    const int* __restrict__ ids, const float* __restrict__ emb,
    const unsigned short* __restrict__ slab, const float* __restrict__ ctot,
    const float* __restrict__ b3, const float* __restrict__ g3, const float* __restrict__ be3,
    const float* __restrict__ b4, const float* __restrict__ g4, const float* __restrict__ be4,
    const float* __restrict__ b5, const float* __restrict__ g5, const float* __restrict__ be5,
    unsigned* __restrict__ featbuf) {
  __shared__ alignas(16) unsigned short Xt[68 * 264];
  __shared__ int ids_s[68];
  const int tid = threadIdx.x;
  const int blk = blockIdx.x;
  const int b = blk >> 3;
  const int t0 = (blk & 7) * 64;
  const int lane = tid & 63;
  const int wave = tid >> 6;
  const int m15 = lane & 15;
  const int quad = lane >> 4;

  if (tid < 68) {
    int t = t0 + tid;
    ids_s[tid] = (t < 512) ? ids[b * 512 + t] : -1;
  }
  __syncthreads();

  // per-lane B-fragment base; frag(e,kc2,nt) = fb0 + e*8192 + kc2*4096 + nt*128
  const unsigned short* fb0 = slab + ((size_t)quad * 128 + wave * 2 * 16 + m15) * 8;
  bf16x8 fA[4], fB[4], fC[4], fD[4];   // [kc2*2+nt], 4-deep entry pipeline
#define LDFRAG(DST, EN)                                                         \
  {                                                                             \
    const unsigned short* p_ = fb0 + (EN) * 8192;                               \
    DST[0] = *(const bf16x8*)(p_);                                              \
    DST[1] = *(const bf16x8*)(p_ + 128);                                        \
    DST[2] = *(const bf16x8*)(p_ + 4096);                                       \
    DST[3] = *(const bf16x8*)(p_ + 4096 + 128);                                 \
  }
  LDFRAG(fA, 0) LDFRAG(fB, 1) LDFRAG(fC, 2) LDFRAG(fD, 3)

  // gather + fp32->bf16 X tile (overlaps the frag loads above)
  for (int i = tid; i < 68 * 64; i += 256) {
    int row = i >> 6, s4 = i & 63;
    uint2 v = make_uint2(0u, 0u);
    int id = ids_s[row];
    if (id >= 0) {
      const float4 f = *(const float4*)(emb + (size_t)id * 256 + s4 * 4);
      v.x = (unsigned)f2bf(f.x) | ((unsigned)f2bf(f.y) << 16);
      v.y = (unsigned)f2bf(f.z) | ((unsigned)f2bf(f.w) << 16);
    }
    *(uint2*)&Xt[row * 264 + s4 * 4] = v;
  }
  __syncthreads();  // Xt ready; no further barriers

  f32x4 acc[4][2];
#pragma unroll
  for (int mt = 0; mt < 4; ++mt)
#pragma unroll
    for (int nt = 0; nt < 2; ++nt) acc[mt][nt] = (f32x4){0.f, 0.f, 0.f, 0.f};

#define ENTRY(KCQ, FR)                                                          \
  {                                                                             \
    _Pragma("unroll")                                                           \
    for (int kc2 = 0; kc2 < 2; ++kc2) {                                         \
      const int kd0 = ((KCQ) * 2 + kc2) * 32 + quad * 8;                        \
      bf16x8 af[4];                                                             \
      _Pragma("unroll")                                                         \
      for (int mt = 0; mt < 4; ++mt)                                            \
        af[mt] = *(const bf16x8*)&Xt[(shift + mt * 16 + m15) * 264 + kd0];      \
      _Pragma("unroll")                                                         \
      for (int mt = 0; mt < 4; ++mt) {                                          \
        acc[mt][0] = __builtin_amdgcn_mfma_f32_16x16x32_bf16(af[mt], FR[kc2 * 2 + 0], acc[mt][0], 0, 0, 0); \
        acc[mt][1] = __builtin_amdgcn_mfma_f32_16x16x32_bf16(af[mt], FR[kc2 * 2 + 1], acc[mt][1], 0, 0, 0); \
      }                                                                         \
    }                                                                           \
  }

  // entries e = eq*4 + j; slice = eq; kcq = j; epilogues at eq 2,6,11,12,13.
  for (int eq = 0; eq < 14; ++eq) {
    const int shift = (eq < 3) ? eq : (eq < 7) ? (eq - 3) : (eq < 12) ? (eq - 7) : 0;

    ENTRY(0, fA) if (eq < 13) LDFRAG(fA, (eq + 1) * 4 + 0)
    ENTRY(1, fB) if (eq < 13) LDFRAG(fB, (eq + 1) * 4 + 1)
    ENTRY(2, fC) if (eq < 13) LDFRAG(fC, (eq + 1) * 4 + 2)
    ENTRY(3, fD) if (eq < 13) LDFRAG(fD, (eq + 1) * 4 + 3)

    const int g = (eq == 2) ? 0 : (eq == 6) ? 1 : (eq == 11) ? 2
                : (eq == 12) ? 3 : (eq == 13) ? 4 : -1;
    if (g >= 0) {
      if (g < 3) {
        const int kk = g + 3;
        const float* bb  = (g == 0) ? b3 : (g == 1) ? b4 : b5;
        const float* gg  = (g == 0) ? g3 : (g == 1) ? g4 : g5;
        const float* bbe = (g == 0) ? be3 : (g == 1) ? be4 : be5;
        const int off = 256 + g * 128;     // feats: [node 256][p3 128][p4 128][p5 128]
        const int tmax = 512 - kk;
#pragma unroll
        for (int nt = 0; nt < 2; ++nt) {
          const int n = (wave * 2 + nt) * 16 + m15;
          const float sc = gg[n] * 0.9999950000375f;  // g * 1/sqrt(1+1e-5)
          const float sh = fmaf(sc, bb[n], bbe[n]);
          float mx = 0.f;  // relu floor doubles as init
#pragma unroll
          for (int mt = 0; mt < 4; ++mt)
#pragma unroll
            for (int r = 0; r < 4; ++r) {
              const int t = t0 + mt * 16 + quad * 4 + r;
              const float v = fmaf(sc, acc[mt][nt][r], sh);
              if (t <= tmax) mx = fmaxf(mx, v);
            }
          mx = fmaxf(mx, __shfl_xor(mx, 16));
          mx = fmaxf(mx, __shfl_xor(mx, 32));
          if (quad == 0) atomicMax(&featbuf[b * 640 + off + n], __float_as_uint(mx));
        }
      } else {
        const int base = (g == 3) ? 0 : 128;
#pragma unroll
        for (int nt = 0; nt < 2; ++nt) {
          const int n = (wave * 2 + nt) * 16 + m15;
          const float ct = ctot[base + n];
          float mx = -3.4e38f;
#pragma unroll
          for (int mt = 0; mt < 4; ++mt)
#pragma unroll
            for (int r = 0; r < 4; ++r)
              mx = fmaxf(mx, acc[mt][nt][r] + ct);
          mx = fmaxf(mx, __shfl_xor(mx, 16));
          mx = fmaxf(mx, __shfl_xor(mx, 32));
          if (quad == 0) {
            unsigned bits = __float_as_uint(mx);
            unsigned key = (bits & 0x80000000u) ? ~bits : (bits | 0x80000000u);  // order-preserving
            atomicMax(&featbuf[b * 640 + base + n], key);
          }
        }
      }
#pragma unroll
      for (int mt = 0; mt < 4; ++mt)
#pragma unroll
        for (int nt = 0; nt < 2; ++nt) acc[mt][nt] = (f32x4){0.f, 0.f, 0.f, 0.f};
    }
  }
#undef ENTRY
#undef LDFRAG
}

// ---------------- classifier ----------------
__global__ void k_fin(const unsigned* __restrict__ featbuf, const float* __restrict__ wc,
                      const float* __restrict__ bc, float* __restrict__ out) {
  int b = blockIdx.x, lane = threadIdx.x;  // 64 threads = 1 wave
  float p[10];
#pragma unroll
  for (int c = 0; c < 10; ++c) p[c] = 0.f;
  for (int f = lane; f < 640; f += 64) {
    unsigned u = featbuf[b * 640 + f];
    float v;
    if (f < 256) v = (u & 0x80000000u) ? __uint_as_float(u ^ 0x80000000u) : __uint_as_float(~u);
    else v = __uint_as_float(u);
#pragma unroll
    for (int c = 0; c < 10; ++c) p[c] = fmaf(v, wc[c * 640 + f], p[c]);
  }
#pragma unroll
  for (int c = 0; c < 10; ++c) {
    float s = p[c];
#pragma unroll
    for (int off = 32; off > 0; off >>= 1) s += __shfl_down(s, off);
    if (lane == 0) out[b * 10 + c] = s + bc[c];
  }
}

// ---------------- launcher ----------------
extern "C" void kernel_launch(void* const* d_in, const int* in_sizes, int n_in,
                              void* d_out, int out_size, void* d_ws, size_t ws_size,
                              hipStream_t stream) {
  (void)in_sizes; (void)n_in; (void)out_size; (void)ws_size;
  const int*   ids  = (const int*)d_in[0];
  const float* emb  = (const float*)d_in[1];
  const float* W    = (const float*)d_in[2];
  const float* bode = (const float*)d_in[3];
  const float* w3   = (const float*)d_in[4];
  const float* b3   = (const float*)d_in[5];
  const float* g3   = (const float*)d_in[6];
  const float* be3  = (const float*)d_in[7];
  const float* w4   = (const float*)d_in[8];
  const float* b4   = (const float*)d_in[9];
  const float* g4   = (const float*)d_in[10];
  const float* be4  = (const float*)d_in[11];
  const float* w5   = (const float*)d_in[12];
  const float* b5   = (const float*)d_in[13];
  const float* g5   = (const float*)d_in[14];
  const float* be5  = (const float*)d_in[15];
  const float* wc   = (const float*)d_in[16];
  const float* bc   = (const float*)d_in[17];
  float* out = (float*)d_out;

  float* wsf = (float*)d_ws;
  // ws layout (floats): B 0 | N2 65536 | c1 131072 | c10 131328 |
  // slab 131584 (14*32768 bf16 = 229376 floats) | featbuf 360960 (40960 uints)
  float* Bm  = wsf;
  float* N2  = wsf + 65536;
  float* c1  = wsf + 131072;
  float* c10 = wsf + 131328;
  unsigned short* slab = (unsigned short*)(wsf + 131584);
  unsigned* featbuf = (unsigned*)(wsf + 360960);

  hipLaunchKernelGGL(k_prep1, dim3(352), dim3(1024), 0, stream,
                     W, bode, w3, w4, w5, Bm, c1, slab, featbuf);
  hipLaunchKernelGGL(k_prep2, dim3(256), dim3(1024), 0, stream, Bm, N2);
  hipLaunchKernelGGL(k_prep3, dim3(257), dim3(1024), 0, stream, Bm, N2, c1, c10, slab);
  hipLaunchKernelGGL(k_main, dim3(512), dim3(256), 0, stream,
                     ids, emb, slab, c10,
                     b3, g3, be3, b4, g4, be4, b5, g5, be5, featbuf);
  hipLaunchKernelGGL(k_fin, dim3(64), dim3(64), 0, stream, featbuf, wc, bc, out);
}